// Round 5
// baseline (158.090 us; speedup 1.0000x reference)
//
#include <hip/hip_runtime.h>
#include <hip/hip_bf16.h>
#include <stdint.h>
#include <stddef.h>

#define L_LEN 4096
#define CIN   128
#define COUT  128
#define NB    32
#define KTOT  384            // 3 * CIN; kappa = t*32 + q*8 + j
#define ROWS  130            // fallback tile halo rows

typedef __bf16 bf16x8 __attribute__((ext_vector_type(8)));
typedef float  f32x4  __attribute__((ext_vector_type(4)));

__device__ __forceinline__ uint16_t f2bf(float f) {
    union { float f; uint32_t u; } v; v.f = f;
    return (uint16_t)((v.u + 0x7fffu + ((v.u >> 16) & 1u)) >> 16);  // RNE
}
__device__ __forceinline__ uint32_t pack2(float lo, float hi) {
    return (uint32_t)f2bf(lo) | ((uint32_t)f2bf(hi) << 16);
}

// ---- prep: transpose-role blocks build xT[b][h][i] (bf16); combine-role
//      blocks build Wc2 (frag-major: (((b*12+t)*8+og)*64+lane)*8+j) + cbias ----
__global__ __launch_bounds__(256) void geps_prep(
    const float* __restrict__ in,
    const float* __restrict__ codes, const float* __restrict__ weight,
    const float* __restrict__ Amat,  const float* __restrict__ Bmat,
    const float* __restrict__ bias,  const float* __restrict__ bias_ctx,
    uint16_t* __restrict__ Wc2, float* __restrict__ cbias,
    uint16_t* __restrict__ xT, int t_blocks)
{
    __shared__ uint16_t __attribute__((aligned(16))) Xt[128 * 128];
    const int tid = threadIdx.x;

    if ((int)blockIdx.x < t_blocks) {
        // ---- transpose role: 128h x 128i tile ----
        const int b  = blockIdx.x >> 5;
        const int h0 = (blockIdx.x & 31) << 7;
        const float* inb = in + ((size_t)b << 19);       // b*128*4096
        #pragma unroll
        for (int it = 0; it < 4; ++it) {
            int task = it * 256 + tid;                   // 1024 tasks
            int p4 = task >> 5, qd = task & 31;          // i-quad, h-quad
            const float* r0 = inb + (size_t)(p4 << 2) * L_LEN + h0 + (qd << 2);
            float4 a0 = *(const float4*)(r0);
            float4 a1 = *(const float4*)(r0 + L_LEN);
            float4 a2 = *(const float4*)(r0 + 2 * L_LEN);
            float4 a3 = *(const float4*)(r0 + 3 * L_LEN);
            const int off = (p4 << 2) & 7, pc = p4 >> 1;
            const float v0[4] = {a0.x, a0.y, a0.z, a0.w};
            const float v1[4] = {a1.x, a1.y, a1.z, a1.w};
            const float v2[4] = {a2.x, a2.y, a2.z, a2.w};
            const float v3[4] = {a3.x, a3.y, a3.z, a3.w};
            #pragma unroll
            for (int j = 0; j < 4; ++j) {
                int r  = (qd << 2) + j;
                int ch = pc ^ (r & 15);
                uint2 w; w.x = pack2(v0[j], v1[j]); w.y = pack2(v2[j], v3[j]);
                *(uint2*)&Xt[r * 128 + (ch << 3) + off] = w;
            }
        }
        __syncthreads();
        // phase 2: wave writes are perfectly contiguous (addr = task*16)
        uint16_t* dst = xT + (((size_t)b << 12) + h0) * 128;
        #pragma unroll
        for (int it = 0; it < 8; ++it) {
            int task = it * 256 + tid;                   // 2048 tasks
            int r = task >> 4, c = task & 15;
            uint4 v = *(const uint4*)&Xt[r * 128 + ((c ^ (r & 15)) << 3)];
            *(uint4*)&dst[(size_t)task << 3] = v;
        }
    } else {
        // ---- combine role: 4 Wc2 elements per thread ----
        int rb = blockIdx.x - t_blocks;                  // 0..1535
        int e0 = (rb << 10) + (tid << 2);
        int lane = (e0 >> 3) & 63, og = (e0 >> 9) & 7, x = e0 >> 12;
        int b = x / 12, t = x - b * 12;
        int o = (og << 4) + (lane & 15);
        int kap0 = t * 32 + ((lane >> 4) << 3) + (e0 & 7);
        uint16_t tmp[4];
        #pragma unroll
        for (int d = 0; d < 4; ++d) {
            int kap = kap0 + d;
            int k = kap >> 7, i = kap & 127;
            float cw = 0.f;
            #pragma unroll
            for (int c = 0; c < 2; ++c) {
                float a = Amat[i * 6 + c * 3 + k];
                #pragma unroll
                for (int r = 0; r < 2; ++r)
                    cw += a * codes[b * 4 + c * 2 + r] * Bmat[o * 6 + r * 3 + k];
            }
            tmp[d] = f2bf(weight[o * 384 + i * 3 + k] + cw);  // FACTOR = 1
        }
        uint2 w;
        w.x = (uint32_t)tmp[0] | ((uint32_t)tmp[1] << 16);
        w.y = (uint32_t)tmp[2] | ((uint32_t)tmp[3] << 16);
        *(uint2*)&Wc2[e0] = w;
        if (rb < 16) {
            int e = (rb << 8) + tid;                     // 4096 cbias entries
            int bb = e >> 7, oo = e & 127;
            float cb = bias[oo];
            #pragma unroll
            for (int c = 0; c < 2; ++c)
                cb += codes[bb * 4 + c * 2 + c] * bias_ctx[c * 128 + oo];
            cbias[e] = cb;
        }
    }
}

// ---- gemm: barrier-free, zero-LDS. M=h (A from xT), N=o (B from Wc2).
//      C/D: col(lane&15)=o, rows(q*4+reg)=4 consecutive h -> f32x4 stores. ----
__global__ __launch_bounds__(256, 3) void geps_gemm(
    const uint16_t* __restrict__ xT, const uint16_t* __restrict__ Wc2,
    const float* __restrict__ cbias, float* __restrict__ out)
{
    const int id  = blockIdx.x;
    const int xcd = id & 7, lin = id >> 3;               // XCD-affinity swizzle
    const int b   = (xcd << 2) + (lin >> 5);
    const int h0  = (lin & 31) << 7;
    const int tid = threadIdx.x, lane = tid & 63, wid = tid >> 6;
    const int m16 = lane & 15, q = lane >> 4;
    const int hq  = (wid & 1) << 6;                      // wave h-offset
    const int oq  = (wid >> 1) << 6;                     // wave o-offset

    const uint16_t* xb = xT  + ((size_t)b << 19);        // b*4096*128
    const uint16_t* wb = Wc2 + (size_t)b * 49152;        // b*12*8*512

    float cbv[4];
    #pragma unroll
    for (int nt = 0; nt < 4; ++nt)
        cbv[nt] = cbias[(b << 7) + oq + (nt << 4) + m16];

    f32x4 acc[4][4];
    #pragma unroll
    for (int a = 0; a < 4; ++a)
        #pragma unroll
        for (int c = 0; c < 4; ++c) acc[a][c] = 0.0f;

    #pragma unroll 2
    for (int t = 0; t < 12; ++t) {
        const int k1 = (t >> 2) - 1;
        const int ib = ((t & 3) << 5) + (q << 3);
        bf16x8 af[4], bfr[4];
        #pragma unroll
        for (int mt = 0; mt < 4; ++mt) {
            int hr = (h0 + hq + (mt << 4) + m16 + k1) & (L_LEN - 1);
            af[mt] = *(const bf16x8*)&xb[((size_t)hr << 7) + ib];
        }
        const uint16_t* wt = wb + ((size_t)(t * 8 + (oq >> 4)) << 9) + (lane << 3);
        #pragma unroll
        for (int nt = 0; nt < 4; ++nt)
            bfr[nt] = *(const bf16x8*)(wt + ((size_t)nt << 9));
        #pragma unroll
        for (int mt = 0; mt < 4; ++mt)
            #pragma unroll
            for (int nt = 0; nt < 4; ++nt)
                acc[mt][nt] = __builtin_amdgcn_mfma_f32_16x16x32_bf16(
                    af[mt], bfr[nt], acc[mt][nt], 0, 0, 0);
    }

    float* ob = out + ((size_t)b << 7) * L_LEN;
    #pragma unroll
    for (int nt = 0; nt < 4; ++nt) {
        const int o = oq + (nt << 4) + m16;
        const float bv = cbv[nt];
        #pragma unroll
        for (int mt = 0; mt < 4; ++mt) {
            const int h = h0 + hq + (mt << 4) + (q << 2);
            f32x4 v = acc[mt][nt] + bv;
            *(f32x4*)&ob[((size_t)o << 12) + h] = v;
        }
    }
}

// ---- fallback (small ws): fused conv, same orientation, in-block Xt ----
__global__ __launch_bounds__(256, 3) void geps_conv_fused(
    const float* __restrict__ in, const uint16_t* __restrict__ Wc2,
    const float* __restrict__ cbias, float* __restrict__ out)
{
    __shared__ uint16_t __attribute__((aligned(16))) Xt[ROWS * 128];
    const int id  = blockIdx.x;
    const int xcd = id & 7, lin = id >> 3;
    const int b   = (xcd << 2) + (lin >> 5);
    const int h0  = (lin & 31) << 7;
    const int tid = threadIdx.x, lane = tid & 63, wid = tid >> 6;
    const int m16 = lane & 15, q = lane >> 4;
    const int hq  = (wid & 1) << 6, oq = (wid >> 1) << 6;

    const float* inb = in + ((size_t)b << 19);
    #pragma unroll
    for (int it = 0; it < 4; ++it) {
        int task = it * 256 + tid;
        int p4 = task >> 5, qd = task & 31;
        const float* r0 = inb + (size_t)(p4 << 2) * L_LEN + h0 + (qd << 2);
        float4 a0 = *(const float4*)(r0);
        float4 a1 = *(const float4*)(r0 + L_LEN);
        float4 a2 = *(const float4*)(r0 + 2 * L_LEN);
        float4 a3 = *(const float4*)(r0 + 3 * L_LEN);
        const int off = (p4 << 2) & 7, pc = p4 >> 1;
        const float v0[4] = {a0.x, a0.y, a0.z, a0.w};
        const float v1[4] = {a1.x, a1.y, a1.z, a1.w};
        const float v2[4] = {a2.x, a2.y, a2.z, a2.w};
        const float v3[4] = {a3.x, a3.y, a3.z, a3.w};
        #pragma unroll
        for (int j = 0; j < 4; ++j) {
            int r  = 1 + (qd << 2) + j;
            int ch = pc ^ (r & 15);
            uint2 w; w.x = pack2(v0[j], v1[j]); w.y = pack2(v2[j], v3[j]);
            *(uint2*)&Xt[r * 128 + (ch << 3) + off] = w;
        }
    }
    if (tid < 128) {
        int p = tid & 63, side = tid >> 6;
        int r = side ? (ROWS - 1) : 0;
        int gh = (h0 - 1 + r) & (L_LEN - 1);
        float x0 = inb[(size_t)(2 * p) * L_LEN + gh];
        float x1 = inb[(size_t)(2 * p + 1) * L_LEN + gh];
        int ch = (p >> 2) ^ (r & 15);
        *(uint32_t*)&Xt[r * 128 + (ch << 3) + ((2 * p) & 7)] = pack2(x0, x1);
    }

    const uint16_t* wb = Wc2 + (size_t)b * 49152;
    float cbv[4];
    #pragma unroll
    for (int nt = 0; nt < 4; ++nt)
        cbv[nt] = cbias[(b << 7) + oq + (nt << 4) + m16];

    f32x4 acc[4][4];
    #pragma unroll
    for (int a = 0; a < 4; ++a)
        #pragma unroll
        for (int c = 0; c < 4; ++c) acc[a][c] = 0.0f;

    __syncthreads();

    #pragma unroll 2
    for (int t = 0; t < 12; ++t) {
        const int k = t >> 2;
        const int i0c = (t & 3) << 2;
        bf16x8 af[4], bfr[4];
        #pragma unroll
        for (int mt = 0; mt < 4; ++mt) {
            int r  = hq + (mt << 4) + m16 + k;           // Xt row = h_local + k
            int ch = (i0c + q) ^ (r & 15);
            af[mt] = *(const bf16x8*)&Xt[r * 128 + (ch << 3)];
        }
        const uint16_t* wt = wb + ((size_t)(t * 8 + (oq >> 4)) << 9) + (lane << 3);
        #pragma unroll
        for (int nt = 0; nt < 4; ++nt)
            bfr[nt] = *(const bf16x8*)(wt + ((size_t)nt << 9));
        #pragma unroll
        for (int mt = 0; mt < 4; ++mt)
            #pragma unroll
            for (int nt = 0; nt < 4; ++nt)
                acc[mt][nt] = __builtin_amdgcn_mfma_f32_16x16x32_bf16(
                    af[mt], bfr[nt], acc[mt][nt], 0, 0, 0);
    }

    float* ob = out + ((size_t)b << 7) * L_LEN;
    #pragma unroll
    for (int nt = 0; nt < 4; ++nt) {
        const int o = oq + (nt << 4) + m16;
        const float bv = cbv[nt];
        #pragma unroll
        for (int mt = 0; mt < 4; ++mt) {
            const int h = h0 + hq + (mt << 4) + (q << 2);
            f32x4 v = acc[mt][nt] + bv;
            *(f32x4*)&ob[((size_t)o << 12) + h] = v;
        }
    }
}

extern "C" void kernel_launch(void* const* d_in, const int* in_sizes, int n_in,
                              void* d_out, int out_size, void* d_ws, size_t ws_size,
                              hipStream_t stream) {
    const float* input    = (const float*)d_in[0];
    const float* codes    = (const float*)d_in[1];
    const float* weight   = (const float*)d_in[2];
    const float* Amat     = (const float*)d_in[3];
    const float* Bmat     = (const float*)d_in[4];
    const float* bias     = (const float*)d_in[5];
    const float* bias_ctx = (const float*)d_in[6];
    float* out = (float*)d_out;

    const size_t wc2_bytes = (size_t)NB * COUT * KTOT * 2;   // 3 MiB
    const size_t cb_off    = wc2_bytes;
    const size_t xt_off    = wc2_bytes + 16384;              // 16B-aligned
    const size_t xt_bytes  = (size_t)NB * L_LEN * CIN * 2;   // 32 MiB

    uint16_t* Wc2   = (uint16_t*)d_ws;
    float*    cbias = (float*)((char*)d_ws + cb_off);
    uint16_t* xT    = (uint16_t*)((char*)d_ws + xt_off);

    if (ws_size >= xt_off + xt_bytes) {
        geps_prep<<<dim3(1024 + 1536), 256, 0, stream>>>(
            input, codes, weight, Amat, Bmat, bias, bias_ctx,
            Wc2, cbias, xT, 1024);
        geps_gemm<<<dim3(1024), 256, 0, stream>>>(xT, Wc2, cbias, out);
    } else {
        geps_prep<<<dim3(1536), 256, 0, stream>>>(
            input, codes, weight, Amat, Bmat, bias, bias_ctx,
            Wc2, cbias, Wc2 /*unused*/, 0);
        geps_conv_fused<<<dim3(1024), 256, 0, stream>>>(input, Wc2, cbias, out);
    }
}